// Round 12
// baseline (214.132 us; speedup 1.0000x reference)
//
#include <hip/hip_runtime.h>
#include <hip/hip_bf16.h>
#include <hip/hip_fp16.h>

#define NTHREADS 256
#define GTHREADS 512
#define POOL_CHUNK 32
#define BKT_EDGES 4096
#define CAP 8192

typedef __attribute__((ext_vector_type(8))) short short8;
typedef __attribute__((ext_vector_type(4))) float f32x4;

__device__ __forceinline__ unsigned short f32_bf16(float f) {
  unsigned u = __float_as_uint(f);
  u += 0x7FFF + ((u >> 16) & 1);
  return (unsigned short)(u >> 16);
}
__device__ __forceinline__ float bf16_f32(unsigned short h) {
  return __uint_as_float((unsigned)h << 16);
}

// ---------------- W prep (+ cursor init + sums zero) ----------------
// element (col, k) of W^T stored at wt[(k>>3)*1024 + col*8 + (k&7)]

__global__ __launch_bounds__(NTHREADS) void prep_w_kernel(
    const float* __restrict__ W0, const float* __restrict__ W1,
    const float* __restrict__ W2, unsigned short* __restrict__ wt_hi,
    unsigned short* __restrict__ wt_lo, int* __restrict__ cursor,
    float* __restrict__ sums, int NB, int sums_len) {
  int idx = blockIdx.x * NTHREADS + threadIdx.x;  // 0..49151
  if (idx < NB) cursor[idx] = idx * CAP;
  if (idx < sums_len) sums[idx] = 0.f;
  int w = idx >> 14;
  int e = idx & 16383;
  int c = e >> 7, k = e & 127;
  const float* W = (w == 0) ? W0 : ((w == 1) ? W1 : W2);
  float v = W[k * 128 + c];
  unsigned short hi = f32_bf16(v);
  unsigned short lo = f32_bf16(v - bf16_f32(hi));
  size_t off = (size_t)w * 16384 + (k >> 3) * 1024 + c * 8 + (k & 7);
  wt_hi[off] = hi;
  wt_lo[off] = lo;
}

// ---------------- pass B: bucketize edges by dst>>8 ----------------

__global__ __launch_bounds__(NTHREADS) void bucketize_kernel(
    const int* __restrict__ src, const int* __restrict__ dst,
    int* __restrict__ cursor, unsigned* __restrict__ store, int E) {
  __shared__ unsigned packed[BKT_EDGES];      // 16 KB
  __shared__ unsigned char bkt[BKT_EDGES];    // 4 KB
  __shared__ int hist[256];
  __shared__ int base[256];
  const int tid = threadIdx.x;
  const int e0 = blockIdx.x * BKT_EDGES;
  const int cnt = min(BKT_EDGES, E - e0);

  hist[tid] = 0;
  __syncthreads();
  for (int i = tid; i < cnt; i += NTHREADS) {
    int s = src[e0 + i];
    int d = dst[e0 + i];
    packed[i] = ((unsigned)s << 8) | (unsigned)(d & 255);
    int b = d >> 8;
    bkt[i] = (unsigned char)b;
    atomicAdd(&hist[b], 1);
  }
  __syncthreads();
  int h = hist[tid];
  if (h) base[tid] = atomicAdd(&cursor[tid], h);
  __syncthreads();
  hist[tid] = 0;
  __syncthreads();
  for (int i = tid; i < cnt; i += NTHREADS) {
    int b = bkt[i];
    int off = atomicAdd(&hist[b], 1);
    int pos = base[b] + off;
    if (pos < (b + 1) * CAP) store[pos] = packed[i];
  }
}

// ---------------- bucket scan (+ graph bounds) ----------------

__global__ __launch_bounds__(NTHREADS) void bucket_scan_kernel(
    const int* __restrict__ cursor, int* __restrict__ bbase, int NB,
    const int* __restrict__ batch, int* __restrict__ gstart, int n, int G) {
  __shared__ int v[256];
  int t = threadIdx.x;
  int c = (t < NB) ? (cursor[t] - t * CAP) : 0;
  v[t] = c;
  __syncthreads();
  for (int off = 1; off < 256; off <<= 1) {
    int u = (t >= off) ? v[t - off] : 0;
    __syncthreads();
    v[t] += u;
    __syncthreads();
  }
  if (t < NB) bbase[t] = v[t] - c;  // exclusive

  // graph boundaries: gstart[g] = lower_bound(batch, g)
  if (t <= G) {
    int lo = 0, hi = n;
    while (lo < hi) {
      int mid = (lo + hi) >> 1;
      if (batch[mid] < t) lo = mid + 1; else hi = mid;
    }
    gstart[t] = lo;
  }
}

// ---------------- pass C: per-bucket CSR build + dis + rowptr ----------------

__global__ __launch_bounds__(NTHREADS) void build_kernel(
    const unsigned* __restrict__ store, const int* __restrict__ cursor,
    const int* __restrict__ bbase, int* __restrict__ rowptr,
    int* __restrict__ csr_src, float* __restrict__ dis, int n, int E, int NB) {
  __shared__ unsigned eb[CAP];    // 32 KB
  __shared__ unsigned ord[CAP];   // 32 KB
  __shared__ int hist[256];
  __shared__ int scn[256];
  __shared__ int eoff[256];
  const int b = blockIdx.x;
  const int t = threadIdx.x;
  int cnt = min(cursor[b] - b * CAP, CAP);
  const int base = bbase[b];

  for (int i = t; i < cnt; i += NTHREADS) eb[i] = store[(size_t)b * CAP + i];
  hist[t] = 0;
  __syncthreads();
  for (int i = t; i < cnt; i += NTHREADS) atomicAdd(&hist[eb[i] & 255u], 1);
  __syncthreads();

  const int node = b * 256 + t;
  const int deg = hist[t];
  if (node < n) dis[node] = rsqrtf((float)deg + 1.0f);

  scn[t] = deg;
  __syncthreads();
  for (int off = 1; off < 256; off <<= 1) {
    int u = (t >= off) ? scn[t - off] : 0;
    __syncthreads();
    scn[t] += u;
    __syncthreads();
  }
  int excl = scn[t] - deg;
  eoff[t] = excl;
  if (node <= n) rowptr[node] = base + excl;
  if (b == NB - 1 && t == 255) rowptr[n] = E;  // sum of in-degrees == E
  __syncthreads();
  hist[t] = 0;
  __syncthreads();
  for (int i = t; i < cnt; i += NTHREADS) {
    unsigned p = eb[i];
    int dl = p & 255u;
    int off = atomicAdd(&hist[dl], 1);
    ord[eoff[dl] + off] = p >> 8;
  }
  __syncthreads();
  for (int i = t; i < cnt; i += NTHREADS) csr_src[base + i] = (int)ord[i];
}

// ---------------- MFMA dense transform (LDS-staged W, 512 thr / 128 rows) ----------------
// hs[n,128] = fp16( (relu?(in) @ (W_hi+W_lo)) * dis[row] )

template <bool BF16_IN>
__global__ __launch_bounds__(GTHREADS) void gemm_mfma_kernel(
    const void* __restrict__ in_, const unsigned short* __restrict__ wt_hi,
    const unsigned short* __restrict__ wt_lo, const float* __restrict__ dis,
    __half* __restrict__ hs, int n) {
  __shared__ unsigned short Whi[16384];  // 32 KB
  __shared__ unsigned short Wlo[16384];  // 32 KB
  const int tid = threadIdx.x;
  const int wave = tid >> 6, lane = tid & 63;
  const int g = lane >> 4, lr = lane & 15;

  // stage W: 2048 short8 chunks per buffer / 512 threads = 4 each
#pragma unroll
  for (int i = 0; i < 4; ++i) {
    int c = i * GTHREADS + tid;
    ((short8*)Whi)[c] = ((const short8*)wt_hi)[c];
    ((short8*)Wlo)[c] = ((const short8*)wt_lo)[c];
  }

  const int rowbase = blockIdx.x * 128 + wave * 16;
  const int arow = rowbase + lr;
  const int arow_c = (arow < n) ? arow : (n - 1);

  short8 a[4];
  if (BF16_IN) {
    const unsigned short* in = (const unsigned short*)in_;
#pragma unroll
    for (int ks = 0; ks < 4; ++ks) {
      union { short8 v; unsigned short u[8]; } t;
      t.v = *(const short8*)&in[(size_t)arow_c * 128 + ks * 32 + g * 8];
#pragma unroll
      for (int i = 0; i < 8; ++i) t.u[i] = (t.u[i] & 0x8000) ? 0 : t.u[i];  // relu
      a[ks] = t.v;
    }
  } else {
    const float* in = (const float*)in_;
#pragma unroll
    for (int ks = 0; ks < 4; ++ks) {
      union { short8 v; unsigned short u[8]; } t;
      const float* p = &in[(size_t)arow_c * 128 + ks * 32 + g * 8];
#pragma unroll
      for (int i = 0; i < 8; ++i) t.u[i] = f32_bf16(p[i]);
      a[ks] = t.v;
    }
  }

  __syncthreads();

  f32x4 acc[8];
#pragma unroll
  for (int ct = 0; ct < 8; ++ct) acc[ct] = (f32x4){0.f, 0.f, 0.f, 0.f};

#pragma unroll
  for (int ks = 0; ks < 4; ++ks) {
    const int kb = (ks * 4 + g) * 1024 + lr * 8;  // + ct*128
    short8 bf[8];
#pragma unroll
    for (int ct = 0; ct < 8; ++ct) bf[ct] = *(const short8*)&Whi[kb + ct * 128];
#pragma unroll
    for (int ct = 0; ct < 8; ++ct)
      acc[ct] = __builtin_amdgcn_mfma_f32_16x16x32_bf16(a[ks], bf[ct], acc[ct], 0, 0, 0);
#pragma unroll
    for (int ct = 0; ct < 8; ++ct) bf[ct] = *(const short8*)&Wlo[kb + ct * 128];
#pragma unroll
    for (int ct = 0; ct < 8; ++ct)
      acc[ct] = __builtin_amdgcn_mfma_f32_16x16x32_bf16(a[ks], bf[ct], acc[ct], 0, 0, 0);
  }

  float dsv[4];
  int orow[4];
#pragma unroll
  for (int r = 0; r < 4; ++r) {
    orow[r] = rowbase + g * 4 + r;
    dsv[r] = (orow[r] < n) ? dis[orow[r]] : 0.f;
  }
#pragma unroll
  for (int ct = 0; ct < 8; ++ct) {
    int col = ct * 16 + lr;
#pragma unroll
    for (int r = 0; r < 4; ++r) {
      if (orow[r] < n)
        hs[(size_t)orow[r] * 128 + col] = __float2half(acc[ct][r] * dsv[r]);
    }
  }
}

// ---------------- fused aggregation (gather, fp16 operand, bf16 output) ----------------
// out[i] = bf16( dis[i] * (hs[i] + sum_e hs[src_e]) + b )
// index loads vectorized as int4 (wave-uniform broadcast, 4x fewer vmem ops)

__global__ __launch_bounds__(NTHREADS) void agg_kernel(
    const __half2* __restrict__ hs, const int* __restrict__ rowptr,
    const int* __restrict__ csr_src, const float* __restrict__ dis,
    const float* __restrict__ b, unsigned* __restrict__ out, int n) {
  int node = blockIdx.x * (NTHREADS / 64) + (threadIdx.x >> 6);
  int lane = threadIdx.x & 63;
  if (node >= n) return;
  int r0 = rowptr[node];
  int r1 = rowptr[node + 1];
  float di = dis[node];
  const char* hsb = (const char*)hs + lane * 4;  // per-lane base

  float2 acc = __half22float2(hs[(size_t)node * 64 + lane]);  // self loop
  float2 acc2 = make_float2(0.f, 0.f);
  float2 acc3 = make_float2(0.f, 0.f);
  float2 acc4 = make_float2(0.f, 0.f);

  int e = r0;
  // peel to int4 alignment
  for (; e < r1 && (e & 3); ++e) {
    int s0 = csr_src[e];
    float2 f0 = __half22float2(*(const __half2*)(hsb + ((unsigned)s0 << 8)));
    acc.x += f0.x; acc.y += f0.y;
  }
  // 16-edge body: 4 x int4 index loads + 16 gathers
  for (; e + 15 < r1; e += 16) {
    int4 sa = *(const int4*)(csr_src + e);
    int4 sb = *(const int4*)(csr_src + e + 4);
    int4 sc = *(const int4*)(csr_src + e + 8);
    int4 sd = *(const int4*)(csr_src + e + 12);
    int s[16] = {sa.x, sa.y, sa.z, sa.w, sb.x, sb.y, sb.z, sb.w,
                 sc.x, sc.y, sc.z, sc.w, sd.x, sd.y, sd.z, sd.w};
    __half2 v[16];
#pragma unroll
    for (int j = 0; j < 16; ++j)
      v[j] = *(const __half2*)(hsb + ((unsigned)s[j] << 8));
#pragma unroll
    for (int j = 0; j < 16; j += 4) {
      float2 f0 = __half22float2(v[j]);
      float2 f1 = __half22float2(v[j + 1]);
      float2 f2 = __half22float2(v[j + 2]);
      float2 f3 = __half22float2(v[j + 3]);
      acc.x += f0.x; acc.y += f0.y;
      acc2.x += f1.x; acc2.y += f1.y;
      acc3.x += f2.x; acc3.y += f2.y;
      acc4.x += f3.x; acc4.y += f3.y;
    }
  }
  // 4-edge body
  for (; e + 3 < r1; e += 4) {
    int4 s4 = *(const int4*)(csr_src + e);
    float2 f0 = __half22float2(*(const __half2*)(hsb + ((unsigned)s4.x << 8)));
    float2 f1 = __half22float2(*(const __half2*)(hsb + ((unsigned)s4.y << 8)));
    float2 f2 = __half22float2(*(const __half2*)(hsb + ((unsigned)s4.z << 8)));
    float2 f3 = __half22float2(*(const __half2*)(hsb + ((unsigned)s4.w << 8)));
    acc.x += f0.x; acc.y += f0.y;
    acc2.x += f1.x; acc2.y += f1.y;
    acc3.x += f2.x; acc3.y += f2.y;
    acc4.x += f3.x; acc4.y += f3.y;
  }
  // scalar tail
  for (; e < r1; ++e) {
    int s0 = csr_src[e];
    float2 f0 = __half22float2(*(const __half2*)(hsb + ((unsigned)s0 << 8)));
    acc.x += f0.x; acc.y += f0.y;
  }
  acc.x += acc2.x + acc3.x + acc4.x;
  acc.y += acc2.y + acc3.y + acc4.y;

  float2 bb = *(const float2*)&b[lane * 2];
  float rx = fmaf(acc.x, di, bb.x);
  float ry = fmaf(acc.y, di, bb.y);
  unsigned lo = f32_bf16(rx);
  unsigned hi = f32_bf16(ry);
  out[(size_t)node * 64 + lane] = lo | (hi << 16);
}

// ---------------- pooling: chunked segment-sum (batch sorted, bf16 input) ----------------

__global__ __launch_bounds__(NTHREADS) void pool_kernel(
    const unsigned* __restrict__ h, const int* __restrict__ batch,
    float* __restrict__ sums, int n) {
  int wid = blockIdx.x * (NTHREADS / 64) + (threadIdx.x >> 6);
  int lane = threadIdx.x & 63;
  int i0 = wid * POOL_CHUNK;
  if (i0 >= n) return;
  int i1 = min(i0 + POOL_CHUNK, n);

  int g = batch[i0];
  float2 acc = make_float2(0.f, 0.f);
  for (int i = i0; i < i1; ++i) {
    int gi = batch[i];
    if (gi != g) {
      float* sp = &sums[g * 128 + lane * 2];
      atomicAdd(sp, acc.x);
      atomicAdd(sp + 1, acc.y);
      acc = make_float2(0.f, 0.f);
      g = gi;
    }
    unsigned v = h[(size_t)i * 64 + lane];
    acc.x += __uint_as_float(v << 16);
    acc.y += __uint_as_float(v & 0xFFFF0000u);
  }
  float* sp = &sums[g * 128 + lane * 2];
  atomicAdd(sp, acc.x);
  atomicAdd(sp + 1, acc.y);
}

// ---------------- final FC ----------------

__global__ __launch_bounds__(64) void fc_kernel(
    const float* __restrict__ sums, const int* __restrict__ gstart,
    const float* __restrict__ fcW, const float* __restrict__ fcb,
    float* __restrict__ out) {
  int g = blockIdx.x;
  int lane = threadIdx.x;
  float2 v = *(const float2*)&sums[g * 128 + lane * 2];
  float2 w = *(const float2*)&fcW[lane * 2];
  float p = v.x * w.x + v.y * w.y;
#pragma unroll
  for (int off = 32; off > 0; off >>= 1) p += __shfl_down(p, off);
  if (lane == 0) {
    float c = (float)(gstart[g + 1] - gstart[g]);
    out[g] = p / fmaxf(c, 1.0f) + fcb[0];
  }
}

extern "C" void kernel_launch(void* const* d_in, const int* in_sizes, int n_in,
                              void* d_out, int out_size, void* d_ws, size_t ws_size,
                              hipStream_t stream) {
  const float* x   = (const float*)d_in[0];
  const int* eidx  = (const int*)d_in[1];
  const int* batch = (const int*)d_in[2];
  const float* W0  = (const float*)d_in[3];
  const float* b0  = (const float*)d_in[4];
  const float* W1  = (const float*)d_in[5];
  const float* b1  = (const float*)d_in[6];
  const float* W2  = (const float*)d_in[7];
  const float* b2  = (const float*)d_in[8];
  const float* fcW = (const float*)d_in[9];
  const float* fcb = (const float*)d_in[10];
  float* out = (float*)d_out;

  const int N = in_sizes[0] / 128;
  const int E = in_sizes[1] / 2;
  const int G = out_size;
  const int NB = (N + 255) >> 8;  // buckets of 256 nodes

  const int* src = eidx;
  const int* dst = eidx + E;

  char* ws = (char*)d_ws;
  size_t off = 0;
  auto alloc = [&](size_t bytes) {
    void* p = ws + off;
    off = (off + bytes + 255) & ~(size_t)255;
    return p;
  };
  float*          dis    = (float*)         alloc((size_t)N * 4);
  int*            rowptr = (int*)           alloc((size_t)(N + 1) * 4);
  int*            cursor = (int*)           alloc((size_t)NB * 4);
  int*            bbase  = (int*)           alloc((size_t)NB * 4);
  int*            csrsrc = (int*)           alloc((size_t)E * 4);
  unsigned*       store  = (unsigned*)      alloc((size_t)NB * CAP * 4);
  __half*         hsbuf  = (__half*)        alloc((size_t)N * 128 * 2);
  unsigned*       bufA   = (unsigned*)      alloc((size_t)N * 64 * 4);  // bf16x2
  unsigned short* wt_hi  = (unsigned short*)alloc((size_t)3 * 16384 * 2);
  unsigned short* wt_lo  = (unsigned short*)alloc((size_t)3 * 16384 * 2);
  float*          sums   = (float*)         alloc((size_t)G * 128 * 4);
  int*            gstart = (int*)           alloc((size_t)(G + 1) * 4);

  // weight prep (+ cursor init + sums zero) + CSR build + norm + bounds
  prep_w_kernel<<<192, NTHREADS, 0, stream>>>(W0, W1, W2, wt_hi, wt_lo,
                                              cursor, sums, NB, G * 128);
  bucketize_kernel<<<(E + BKT_EDGES - 1) / BKT_EDGES, NTHREADS, 0, stream>>>(
      src, dst, cursor, store, E);
  bucket_scan_kernel<<<1, NTHREADS, 0, stream>>>(cursor, bbase, NB,
                                                 batch, gstart, N, G);
  build_kernel<<<NB, NTHREADS, 0, stream>>>(
      store, cursor, bbase, rowptr, csrsrc, dis, N, E, NB);

  const int gemm_blocks = (N + 127) / 128;
  const int node_blocks = (N + 3) / 4;
  const int pool_waves = (N + POOL_CHUNK - 1) / POOL_CHUNK;

  // layer 0 (f32 input, no relu)
  gemm_mfma_kernel<false><<<gemm_blocks, GTHREADS, 0, stream>>>(
      x, wt_hi, wt_lo, dis, hsbuf, N);
  agg_kernel<<<node_blocks, NTHREADS, 0, stream>>>(
      (const __half2*)hsbuf, rowptr, csrsrc, dis, b0, bufA, N);
  // layer 1 (bf16 input, relu)
  gemm_mfma_kernel<true><<<gemm_blocks, GTHREADS, 0, stream>>>(
      bufA, wt_hi + 16384, wt_lo + 16384, dis, hsbuf, N);
  agg_kernel<<<node_blocks, NTHREADS, 0, stream>>>(
      (const __half2*)hsbuf, rowptr, csrsrc, dis, b1, bufA, N);
  // layer 2 (bf16 input, relu)
  gemm_mfma_kernel<true><<<gemm_blocks, GTHREADS, 0, stream>>>(
      bufA, wt_hi + 32768, wt_lo + 32768, dis, hsbuf, N);
  agg_kernel<<<node_blocks, NTHREADS, 0, stream>>>(
      (const __half2*)hsbuf, rowptr, csrsrc, dis, b2, bufA, N);

  // pool + fc
  pool_kernel<<<(pool_waves + 3) / 4, NTHREADS, 0, stream>>>(bufA, batch, sums, N);
  fc_kernel<<<G, 64, 0, stream>>>(sums, gstart, fcW, fcb, out);
}

// Round 13
// 197.816 us; speedup vs baseline: 1.0825x; 1.0825x over previous
//
#include <hip/hip_runtime.h>
#include <hip/hip_bf16.h>
#include <hip/hip_fp16.h>

#define NTHREADS 256
#define GTHREADS 512
#define POOL_CHUNK 32
#define BKT_EDGES 4096
#define CAP 8192

typedef __attribute__((ext_vector_type(8))) short short8;
typedef __attribute__((ext_vector_type(4))) float f32x4;

__device__ __forceinline__ unsigned short f32_bf16(float f) {
  unsigned u = __float_as_uint(f);
  u += 0x7FFF + ((u >> 16) & 1);
  return (unsigned short)(u >> 16);
}
__device__ __forceinline__ float bf16_f32(unsigned short h) {
  return __uint_as_float((unsigned)h << 16);
}

// ---------------- W prep (+ cursor init + sums zero) ----------------
// element (col, k) of W^T stored at wt[(k>>3)*1024 + col*8 + (k&7)]

__global__ __launch_bounds__(NTHREADS) void prep_w_kernel(
    const float* __restrict__ W0, const float* __restrict__ W1,
    const float* __restrict__ W2, unsigned short* __restrict__ wt_hi,
    unsigned short* __restrict__ wt_lo, int* __restrict__ cursor,
    float* __restrict__ sums, int NB, int sums_len) {
  int idx = blockIdx.x * NTHREADS + threadIdx.x;  // 0..49151
  if (idx < NB) cursor[idx] = idx * CAP;
  if (idx < sums_len) sums[idx] = 0.f;
  int w = idx >> 14;
  int e = idx & 16383;
  int c = e >> 7, k = e & 127;
  const float* W = (w == 0) ? W0 : ((w == 1) ? W1 : W2);
  float v = W[k * 128 + c];
  unsigned short hi = f32_bf16(v);
  unsigned short lo = f32_bf16(v - bf16_f32(hi));
  size_t off = (size_t)w * 16384 + (k >> 3) * 1024 + c * 8 + (k & 7);
  wt_hi[off] = hi;
  wt_lo[off] = lo;
}

// ---------------- pass B: bucketize edges by dst>>8 ----------------

__global__ __launch_bounds__(NTHREADS) void bucketize_kernel(
    const int* __restrict__ src, const int* __restrict__ dst,
    int* __restrict__ cursor, unsigned* __restrict__ store, int E) {
  __shared__ unsigned packed[BKT_EDGES];      // 16 KB
  __shared__ unsigned char bkt[BKT_EDGES];    // 4 KB
  __shared__ int hist[256];
  __shared__ int base[256];
  const int tid = threadIdx.x;
  const int e0 = blockIdx.x * BKT_EDGES;
  const int cnt = min(BKT_EDGES, E - e0);

  hist[tid] = 0;
  __syncthreads();
  for (int i = tid; i < cnt; i += NTHREADS) {
    int s = src[e0 + i];
    int d = dst[e0 + i];
    packed[i] = ((unsigned)s << 8) | (unsigned)(d & 255);
    int b = d >> 8;
    bkt[i] = (unsigned char)b;
    atomicAdd(&hist[b], 1);
  }
  __syncthreads();
  int h = hist[tid];
  if (h) base[tid] = atomicAdd(&cursor[tid], h);
  __syncthreads();
  hist[tid] = 0;
  __syncthreads();
  for (int i = tid; i < cnt; i += NTHREADS) {
    int b = bkt[i];
    int off = atomicAdd(&hist[b], 1);
    int pos = base[b] + off;
    if (pos < (b + 1) * CAP) store[pos] = packed[i];
  }
}

// ---------------- pass C: per-bucket CSR build + dis + rowptr ----------------
// bucket base recomputed per block via LDS scan of all bucket counts (no bbase kernel)

__global__ __launch_bounds__(NTHREADS) void build_kernel(
    const unsigned* __restrict__ store, const int* __restrict__ cursor,
    int* __restrict__ rowptr, int* __restrict__ csr_src,
    float* __restrict__ dis, int n, int E, int NB) {
  __shared__ unsigned eb[CAP];    // 32 KB
  __shared__ unsigned ord[CAP];   // 32 KB
  __shared__ int bcnt[256];
  __shared__ int bscn[256];
  __shared__ int hist[256];
  __shared__ int scn[256];
  __shared__ int eoff[256];
  const int b = blockIdx.x;
  const int t = threadIdx.x;

  // per-block redundant scan of bucket counts -> base
  int bc = (t < NB) ? (cursor[t] - t * CAP) : 0;
  bcnt[t] = bc;
  bscn[t] = bc;
  __syncthreads();
  for (int off = 1; off < 256; off <<= 1) {
    int u = (t >= off) ? bscn[t - off] : 0;
    __syncthreads();
    bscn[t] += u;
    __syncthreads();
  }
  const int base = bscn[b] - bcnt[b];   // exclusive scan at b (uniform across block)
  const int cnt = min(bcnt[b], CAP);

  for (int i = t; i < cnt; i += NTHREADS) eb[i] = store[(size_t)b * CAP + i];
  hist[t] = 0;
  __syncthreads();
  for (int i = t; i < cnt; i += NTHREADS) atomicAdd(&hist[eb[i] & 255u], 1);
  __syncthreads();

  const int node = b * 256 + t;
  const int deg = hist[t];
  if (node < n) dis[node] = rsqrtf((float)deg + 1.0f);

  scn[t] = deg;
  __syncthreads();
  for (int off = 1; off < 256; off <<= 1) {
    int u = (t >= off) ? scn[t - off] : 0;
    __syncthreads();
    scn[t] += u;
    __syncthreads();
  }
  int excl = scn[t] - deg;
  eoff[t] = excl;
  if (node <= n) rowptr[node] = base + excl;
  if (b == NB - 1 && t == 255) rowptr[n] = E;  // sum of in-degrees == E
  __syncthreads();
  hist[t] = 0;
  __syncthreads();
  for (int i = t; i < cnt; i += NTHREADS) {
    unsigned p = eb[i];
    int dl = p & 255u;
    int off = atomicAdd(&hist[dl], 1);
    ord[eoff[dl] + off] = p >> 8;
  }
  __syncthreads();
  for (int i = t; i < cnt; i += NTHREADS) csr_src[base + i] = (int)ord[i];
}

// ---------------- MFMA dense transform (LDS-staged W, 512 thr / 128 rows) ----------------
// hs[n,128] = fp16( (relu?(in) @ (W_hi+W_lo)) * dis[row] )

template <bool BF16_IN>
__global__ __launch_bounds__(GTHREADS) void gemm_mfma_kernel(
    const void* __restrict__ in_, const unsigned short* __restrict__ wt_hi,
    const unsigned short* __restrict__ wt_lo, const float* __restrict__ dis,
    __half* __restrict__ hs, int n) {
  __shared__ unsigned short Whi[16384];  // 32 KB
  __shared__ unsigned short Wlo[16384];  // 32 KB
  const int tid = threadIdx.x;
  const int wave = tid >> 6, lane = tid & 63;
  const int g = lane >> 4, lr = lane & 15;

  // stage W: 2048 short8 chunks per buffer / 512 threads = 4 each
#pragma unroll
  for (int i = 0; i < 4; ++i) {
    int c = i * GTHREADS + tid;
    ((short8*)Whi)[c] = ((const short8*)wt_hi)[c];
    ((short8*)Wlo)[c] = ((const short8*)wt_lo)[c];
  }

  const int rowbase = blockIdx.x * 128 + wave * 16;
  const int arow = rowbase + lr;
  const int arow_c = (arow < n) ? arow : (n - 1);

  short8 a[4];
  if (BF16_IN) {
    const unsigned short* in = (const unsigned short*)in_;
#pragma unroll
    for (int ks = 0; ks < 4; ++ks) {
      union { short8 v; unsigned short u[8]; } t;
      t.v = *(const short8*)&in[(size_t)arow_c * 128 + ks * 32 + g * 8];
#pragma unroll
      for (int i = 0; i < 8; ++i) t.u[i] = (t.u[i] & 0x8000) ? 0 : t.u[i];  // relu
      a[ks] = t.v;
    }
  } else {
    const float* in = (const float*)in_;
#pragma unroll
    for (int ks = 0; ks < 4; ++ks) {
      union { short8 v; unsigned short u[8]; } t;
      const float* p = &in[(size_t)arow_c * 128 + ks * 32 + g * 8];
#pragma unroll
      for (int i = 0; i < 8; ++i) t.u[i] = f32_bf16(p[i]);
      a[ks] = t.v;
    }
  }

  __syncthreads();

  f32x4 acc[8];
#pragma unroll
  for (int ct = 0; ct < 8; ++ct) acc[ct] = (f32x4){0.f, 0.f, 0.f, 0.f};

#pragma unroll
  for (int ks = 0; ks < 4; ++ks) {
    const int kb = (ks * 4 + g) * 1024 + lr * 8;  // + ct*128
    short8 bf[8];
#pragma unroll
    for (int ct = 0; ct < 8; ++ct) bf[ct] = *(const short8*)&Whi[kb + ct * 128];
#pragma unroll
    for (int ct = 0; ct < 8; ++ct)
      acc[ct] = __builtin_amdgcn_mfma_f32_16x16x32_bf16(a[ks], bf[ct], acc[ct], 0, 0, 0);
#pragma unroll
    for (int ct = 0; ct < 8; ++ct) bf[ct] = *(const short8*)&Wlo[kb + ct * 128];
#pragma unroll
    for (int ct = 0; ct < 8; ++ct)
      acc[ct] = __builtin_amdgcn_mfma_f32_16x16x32_bf16(a[ks], bf[ct], acc[ct], 0, 0, 0);
  }

  float dsv[4];
  int orow[4];
#pragma unroll
  for (int r = 0; r < 4; ++r) {
    orow[r] = rowbase + g * 4 + r;
    dsv[r] = (orow[r] < n) ? dis[orow[r]] : 0.f;
  }
#pragma unroll
  for (int ct = 0; ct < 8; ++ct) {
    int col = ct * 16 + lr;
#pragma unroll
    for (int r = 0; r < 4; ++r) {
      if (orow[r] < n)
        hs[(size_t)orow[r] * 128 + col] = __float2half(acc[ct][r] * dsv[r]);
    }
  }
}

// ---------------- fused aggregation (gather, fp16 operand, bf16 output) ----------------
// out[i] = bf16( dis[i] * (hs[i] + sum_e hs[src_e]) + b )

__global__ __launch_bounds__(NTHREADS) void agg_kernel(
    const __half2* __restrict__ hs, const int* __restrict__ rowptr,
    const int* __restrict__ csr_src, const float* __restrict__ dis,
    const float* __restrict__ b, unsigned* __restrict__ out, int n) {
  int node = blockIdx.x * (NTHREADS / 64) + (threadIdx.x >> 6);
  int lane = threadIdx.x & 63;
  if (node >= n) return;
  int r0 = rowptr[node];
  int r1 = rowptr[node + 1];
  float di = dis[node];
  const char* hsb = (const char*)hs + lane * 4;  // per-lane base

  float2 acc = __half22float2(hs[(size_t)node * 64 + lane]);  // self loop
  float2 acc2 = make_float2(0.f, 0.f);
  float2 acc3 = make_float2(0.f, 0.f);
  float2 acc4 = make_float2(0.f, 0.f);

  int e = r0;
  for (; e + 15 < r1; e += 16) {
    int s[16];
#pragma unroll
    for (int j = 0; j < 16; ++j) s[j] = csr_src[e + j];
    __half2 v[16];
#pragma unroll
    for (int j = 0; j < 16; ++j)
      v[j] = *(const __half2*)(hsb + ((unsigned)s[j] << 8));
#pragma unroll
    for (int j = 0; j < 16; j += 4) {
      float2 f0 = __half22float2(v[j]);
      float2 f1 = __half22float2(v[j + 1]);
      float2 f2 = __half22float2(v[j + 2]);
      float2 f3 = __half22float2(v[j + 3]);
      acc.x += f0.x; acc.y += f0.y;
      acc2.x += f1.x; acc2.y += f1.y;
      acc3.x += f2.x; acc3.y += f2.y;
      acc4.x += f3.x; acc4.y += f3.y;
    }
  }
  for (; e + 3 < r1; e += 4) {
    int s0 = csr_src[e], s1 = csr_src[e + 1], s2 = csr_src[e + 2], s3 = csr_src[e + 3];
    float2 f0 = __half22float2(*(const __half2*)(hsb + ((unsigned)s0 << 8)));
    float2 f1 = __half22float2(*(const __half2*)(hsb + ((unsigned)s1 << 8)));
    float2 f2 = __half22float2(*(const __half2*)(hsb + ((unsigned)s2 << 8)));
    float2 f3 = __half22float2(*(const __half2*)(hsb + ((unsigned)s3 << 8)));
    acc.x += f0.x; acc.y += f0.y;
    acc2.x += f1.x; acc2.y += f1.y;
    acc3.x += f2.x; acc3.y += f2.y;
    acc4.x += f3.x; acc4.y += f3.y;
  }
  for (; e < r1; ++e) {
    int s0 = csr_src[e];
    float2 f0 = __half22float2(*(const __half2*)(hsb + ((unsigned)s0 << 8)));
    acc.x += f0.x; acc.y += f0.y;
  }
  acc.x += acc2.x + acc3.x + acc4.x;
  acc.y += acc2.y + acc3.y + acc4.y;

  float2 bb = *(const float2*)&b[lane * 2];
  float rx = fmaf(acc.x, di, bb.x);
  float ry = fmaf(acc.y, di, bb.y);
  unsigned lo = f32_bf16(rx);
  unsigned hi = f32_bf16(ry);
  out[(size_t)node * 64 + lane] = lo | (hi << 16);
}

// ---------------- pooling: chunked segment-sum (batch sorted, bf16 input) ----------------

__global__ __launch_bounds__(NTHREADS) void pool_kernel(
    const unsigned* __restrict__ h, const int* __restrict__ batch,
    float* __restrict__ sums, int n) {
  int wid = blockIdx.x * (NTHREADS / 64) + (threadIdx.x >> 6);
  int lane = threadIdx.x & 63;
  int i0 = wid * POOL_CHUNK;
  if (i0 >= n) return;
  int i1 = min(i0 + POOL_CHUNK, n);

  int g = batch[i0];
  float2 acc = make_float2(0.f, 0.f);
  for (int i = i0; i < i1; ++i) {
    int gi = batch[i];
    if (gi != g) {
      float* sp = &sums[g * 128 + lane * 2];
      atomicAdd(sp, acc.x);
      atomicAdd(sp + 1, acc.y);
      acc = make_float2(0.f, 0.f);
      g = gi;
    }
    unsigned v = h[(size_t)i * 64 + lane];
    acc.x += __uint_as_float(v << 16);
    acc.y += __uint_as_float(v & 0xFFFF0000u);
  }
  float* sp = &sums[g * 128 + lane * 2];
  atomicAdd(sp, acc.x);
  atomicAdd(sp + 1, acc.y);
}

// ---------------- final FC (graph count via in-kernel binary search) ----------------

__global__ __launch_bounds__(64) void fc_kernel(
    const float* __restrict__ sums, const int* __restrict__ batch,
    const float* __restrict__ fcW, const float* __restrict__ fcb,
    float* __restrict__ out, int n) {
  int g = blockIdx.x;
  int lane = threadIdx.x;
  float2 v = *(const float2*)&sums[g * 128 + lane * 2];
  float2 w = *(const float2*)&fcW[lane * 2];
  float p = v.x * w.x + v.y * w.y;
#pragma unroll
  for (int off = 32; off > 0; off >>= 1) p += __shfl_down(p, off);

  // lanes 0,1: lower_bound(batch, g) / lower_bound(batch, g+1)
  int lb = 0;
  if (lane < 2) {
    int key = g + lane;
    int lo = 0, hi = n;
    while (lo < hi) {
      int mid = (lo + hi) >> 1;
      if (batch[mid] < key) lo = mid + 1; else hi = mid;
    }
    lb = lo;
  }
  int lb0 = __shfl(lb, 0);
  int lb1 = __shfl(lb, 1);
  if (lane == 0) {
    float c = (float)(lb1 - lb0);
    out[g] = p / fmaxf(c, 1.0f) + fcb[0];
  }
}

extern "C" void kernel_launch(void* const* d_in, const int* in_sizes, int n_in,
                              void* d_out, int out_size, void* d_ws, size_t ws_size,
                              hipStream_t stream) {
  const float* x   = (const float*)d_in[0];
  const int* eidx  = (const int*)d_in[1];
  const int* batch = (const int*)d_in[2];
  const float* W0  = (const float*)d_in[3];
  const float* b0  = (const float*)d_in[4];
  const float* W1  = (const float*)d_in[5];
  const float* b1  = (const float*)d_in[6];
  const float* W2  = (const float*)d_in[7];
  const float* b2  = (const float*)d_in[8];
  const float* fcW = (const float*)d_in[9];
  const float* fcb = (const float*)d_in[10];
  float* out = (float*)d_out;

  const int N = in_sizes[0] / 128;
  const int E = in_sizes[1] / 2;
  const int G = out_size;
  const int NB = (N + 255) >> 8;  // buckets of 256 nodes

  const int* src = eidx;
  const int* dst = eidx + E;

  char* ws = (char*)d_ws;
  size_t off = 0;
  auto alloc = [&](size_t bytes) {
    void* p = ws + off;
    off = (off + bytes + 255) & ~(size_t)255;
    return p;
  };
  float*          dis    = (float*)         alloc((size_t)N * 4);
  int*            rowptr = (int*)           alloc((size_t)(N + 1) * 4);
  int*            cursor = (int*)           alloc((size_t)NB * 4);
  int*            csrsrc = (int*)           alloc((size_t)E * 4);
  unsigned*       store  = (unsigned*)      alloc((size_t)NB * CAP * 4);
  __half*         hsbuf  = (__half*)        alloc((size_t)N * 128 * 2);
  unsigned*       bufA   = (unsigned*)      alloc((size_t)N * 64 * 4);  // bf16x2
  unsigned short* wt_hi  = (unsigned short*)alloc((size_t)3 * 16384 * 2);
  unsigned short* wt_lo  = (unsigned short*)alloc((size_t)3 * 16384 * 2);
  float*          sums   = (float*)         alloc((size_t)G * 128 * 4);

  // weight prep (+ cursor init + sums zero) + CSR build + norm
  prep_w_kernel<<<192, NTHREADS, 0, stream>>>(W0, W1, W2, wt_hi, wt_lo,
                                              cursor, sums, NB, G * 128);
  bucketize_kernel<<<(E + BKT_EDGES - 1) / BKT_EDGES, NTHREADS, 0, stream>>>(
      src, dst, cursor, store, E);
  build_kernel<<<NB, NTHREADS, 0, stream>>>(
      store, cursor, rowptr, csrsrc, dis, N, E, NB);

  const int gemm_blocks = (N + 127) / 128;
  const int node_blocks = (N + 3) / 4;
  const int pool_waves = (N + POOL_CHUNK - 1) / POOL_CHUNK;

  // layer 0 (f32 input, no relu)
  gemm_mfma_kernel<false><<<gemm_blocks, GTHREADS, 0, stream>>>(
      x, wt_hi, wt_lo, dis, hsbuf, N);
  agg_kernel<<<node_blocks, NTHREADS, 0, stream>>>(
      (const __half2*)hsbuf, rowptr, csrsrc, dis, b0, bufA, N);
  // layer 1 (bf16 input, relu)
  gemm_mfma_kernel<true><<<gemm_blocks, GTHREADS, 0, stream>>>(
      bufA, wt_hi + 16384, wt_lo + 16384, dis, hsbuf, N);
  agg_kernel<<<node_blocks, NTHREADS, 0, stream>>>(
      (const __half2*)hsbuf, rowptr, csrsrc, dis, b1, bufA, N);
  // layer 2 (bf16 input, relu)
  gemm_mfma_kernel<true><<<gemm_blocks, GTHREADS, 0, stream>>>(
      bufA, wt_hi + 32768, wt_lo + 32768, dis, hsbuf, N);
  agg_kernel<<<node_blocks, NTHREADS, 0, stream>>>(
      (const __half2*)hsbuf, rowptr, csrsrc, dis, b2, bufA, N);

  // pool + fc
  pool_kernel<<<(pool_waves + 3) / 4, NTHREADS, 0, stream>>>(bufA, batch, sums, N);
  fc_kernel<<<G, 64, 0, stream>>>(sums, batch, fcW, fcb, out, N);
}

// Round 14
// 195.759 us; speedup vs baseline: 1.0939x; 1.0105x over previous
//
#include <hip/hip_runtime.h>
#include <hip/hip_bf16.h>
#include <hip/hip_fp16.h>

#define NTHREADS 256
#define GTHREADS 512
#define POOL_CHUNK 32
#define BKT_EDGES 4096
#define CAP 8192

typedef __attribute__((ext_vector_type(8))) short short8;
typedef __attribute__((ext_vector_type(4))) float f32x4;

__device__ __forceinline__ unsigned short f32_bf16(float f) {
  unsigned u = __float_as_uint(f);
  u += 0x7FFF + ((u >> 16) & 1);
  return (unsigned short)(u >> 16);
}
__device__ __forceinline__ float bf16_f32(unsigned short h) {
  return __uint_as_float((unsigned)h << 16);
}
__device__ __forceinline__ float2 h2u(unsigned u) {
  __half2 h;
  *reinterpret_cast<unsigned*>(&h) = u;
  return __half22float2(h);
}

// ---------------- W prep (+ cursor init + sums zero) ----------------
// element (col, k) of W^T stored at wt[(k>>3)*1024 + col*8 + (k&7)]

__global__ __launch_bounds__(NTHREADS) void prep_w_kernel(
    const float* __restrict__ W0, const float* __restrict__ W1,
    const float* __restrict__ W2, unsigned short* __restrict__ wt_hi,
    unsigned short* __restrict__ wt_lo, int* __restrict__ cursor,
    float* __restrict__ sums, int NB, int sums_len) {
  int idx = blockIdx.x * NTHREADS + threadIdx.x;  // 0..49151
  if (idx < NB) cursor[idx] = idx * CAP;
  if (idx < sums_len) sums[idx] = 0.f;
  int w = idx >> 14;
  int e = idx & 16383;
  int c = e >> 7, k = e & 127;
  const float* W = (w == 0) ? W0 : ((w == 1) ? W1 : W2);
  float v = W[k * 128 + c];
  unsigned short hi = f32_bf16(v);
  unsigned short lo = f32_bf16(v - bf16_f32(hi));
  size_t off = (size_t)w * 16384 + (k >> 3) * 1024 + c * 8 + (k & 7);
  wt_hi[off] = hi;
  wt_lo[off] = lo;
}

// ---------------- pass B: bucketize edges by dst>>8 ----------------

__global__ __launch_bounds__(NTHREADS) void bucketize_kernel(
    const int* __restrict__ src, const int* __restrict__ dst,
    int* __restrict__ cursor, unsigned* __restrict__ store, int E) {
  __shared__ unsigned packed[BKT_EDGES];      // 16 KB
  __shared__ unsigned char bkt[BKT_EDGES];    // 4 KB
  __shared__ int hist[256];
  __shared__ int base[256];
  const int tid = threadIdx.x;
  const int e0 = blockIdx.x * BKT_EDGES;
  const int cnt = min(BKT_EDGES, E - e0);

  hist[tid] = 0;
  __syncthreads();
  for (int i = tid; i < cnt; i += NTHREADS) {
    int s = src[e0 + i];
    int d = dst[e0 + i];
    packed[i] = ((unsigned)s << 8) | (unsigned)(d & 255);
    int b = d >> 8;
    bkt[i] = (unsigned char)b;
    atomicAdd(&hist[b], 1);
  }
  __syncthreads();
  int h = hist[tid];
  if (h) base[tid] = atomicAdd(&cursor[tid], h);
  __syncthreads();
  hist[tid] = 0;
  __syncthreads();
  for (int i = tid; i < cnt; i += NTHREADS) {
    int b = bkt[i];
    int off = atomicAdd(&hist[b], 1);
    int pos = base[b] + off;
    if (pos < (b + 1) * CAP) store[pos] = packed[i];
  }
}

// ---------------- pass C: per-bucket CSR build + dis + rowptr ----------------

__global__ __launch_bounds__(NTHREADS) void build_kernel(
    const unsigned* __restrict__ store, const int* __restrict__ cursor,
    int* __restrict__ rowptr, int* __restrict__ csr_src,
    float* __restrict__ dis, int n, int E, int NB) {
  __shared__ unsigned eb[CAP];    // 32 KB
  __shared__ unsigned ord[CAP];   // 32 KB
  __shared__ int bcnt[256];
  __shared__ int bscn[256];
  __shared__ int hist[256];
  __shared__ int scn[256];
  __shared__ int eoff[256];
  const int b = blockIdx.x;
  const int t = threadIdx.x;

  // per-block redundant scan of bucket counts -> base
  int bc = (t < NB) ? (cursor[t] - t * CAP) : 0;
  bcnt[t] = bc;
  bscn[t] = bc;
  __syncthreads();
  for (int off = 1; off < 256; off <<= 1) {
    int u = (t >= off) ? bscn[t - off] : 0;
    __syncthreads();
    bscn[t] += u;
    __syncthreads();
  }
  const int base = bscn[b] - bcnt[b];
  const int cnt = min(bcnt[b], CAP);

  for (int i = t; i < cnt; i += NTHREADS) eb[i] = store[(size_t)b * CAP + i];
  hist[t] = 0;
  __syncthreads();
  for (int i = t; i < cnt; i += NTHREADS) atomicAdd(&hist[eb[i] & 255u], 1);
  __syncthreads();

  const int node = b * 256 + t;
  const int deg = hist[t];
  if (node < n) dis[node] = rsqrtf((float)deg + 1.0f);

  scn[t] = deg;
  __syncthreads();
  for (int off = 1; off < 256; off <<= 1) {
    int u = (t >= off) ? scn[t - off] : 0;
    __syncthreads();
    scn[t] += u;
    __syncthreads();
  }
  int excl = scn[t] - deg;
  eoff[t] = excl;
  if (node <= n) rowptr[node] = base + excl;
  if (b == NB - 1 && t == 255) rowptr[n] = E;
  __syncthreads();
  hist[t] = 0;
  __syncthreads();
  for (int i = t; i < cnt; i += NTHREADS) {
    unsigned p = eb[i];
    int dl = p & 255u;
    int off = atomicAdd(&hist[dl], 1);
    ord[eoff[dl] + off] = p >> 8;
  }
  __syncthreads();
  for (int i = t; i < cnt; i += NTHREADS) csr_src[base + i] = (int)ord[i];
}

// ---------------- MFMA dense transform (LDS-staged W, 512 thr / 128 rows) ----------------

template <bool BF16_IN>
__global__ __launch_bounds__(GTHREADS) void gemm_mfma_kernel(
    const void* __restrict__ in_, const unsigned short* __restrict__ wt_hi,
    const unsigned short* __restrict__ wt_lo, const float* __restrict__ dis,
    __half* __restrict__ hs, int n) {
  __shared__ unsigned short Whi[16384];  // 32 KB
  __shared__ unsigned short Wlo[16384];  // 32 KB
  const int tid = threadIdx.x;
  const int wave = tid >> 6, lane = tid & 63;
  const int g = lane >> 4, lr = lane & 15;

#pragma unroll
  for (int i = 0; i < 4; ++i) {
    int c = i * GTHREADS + tid;
    ((short8*)Whi)[c] = ((const short8*)wt_hi)[c];
    ((short8*)Wlo)[c] = ((const short8*)wt_lo)[c];
  }

  const int rowbase = blockIdx.x * 128 + wave * 16;
  const int arow = rowbase + lr;
  const int arow_c = (arow < n) ? arow : (n - 1);

  short8 a[4];
  if (BF16_IN) {
    const unsigned short* in = (const unsigned short*)in_;
#pragma unroll
    for (int ks = 0; ks < 4; ++ks) {
      union { short8 v; unsigned short u[8]; } t;
      t.v = *(const short8*)&in[(size_t)arow_c * 128 + ks * 32 + g * 8];
#pragma unroll
      for (int i = 0; i < 8; ++i) t.u[i] = (t.u[i] & 0x8000) ? 0 : t.u[i];  // relu
      a[ks] = t.v;
    }
  } else {
    const float* in = (const float*)in_;
#pragma unroll
    for (int ks = 0; ks < 4; ++ks) {
      union { short8 v; unsigned short u[8]; } t;
      const float* p = &in[(size_t)arow_c * 128 + ks * 32 + g * 8];
#pragma unroll
      for (int i = 0; i < 8; ++i) t.u[i] = f32_bf16(p[i]);
      a[ks] = t.v;
    }
  }

  __syncthreads();

  f32x4 acc[8];
#pragma unroll
  for (int ct = 0; ct < 8; ++ct) acc[ct] = (f32x4){0.f, 0.f, 0.f, 0.f};

#pragma unroll
  for (int ks = 0; ks < 4; ++ks) {
    const int kb = (ks * 4 + g) * 1024 + lr * 8;
    short8 bf[8];
#pragma unroll
    for (int ct = 0; ct < 8; ++ct) bf[ct] = *(const short8*)&Whi[kb + ct * 128];
#pragma unroll
    for (int ct = 0; ct < 8; ++ct)
      acc[ct] = __builtin_amdgcn_mfma_f32_16x16x32_bf16(a[ks], bf[ct], acc[ct], 0, 0, 0);
#pragma unroll
    for (int ct = 0; ct < 8; ++ct) bf[ct] = *(const short8*)&Wlo[kb + ct * 128];
#pragma unroll
    for (int ct = 0; ct < 8; ++ct)
      acc[ct] = __builtin_amdgcn_mfma_f32_16x16x32_bf16(a[ks], bf[ct], acc[ct], 0, 0, 0);
  }

  float dsv[4];
  int orow[4];
#pragma unroll
  for (int r = 0; r < 4; ++r) {
    orow[r] = rowbase + g * 4 + r;
    dsv[r] = (orow[r] < n) ? dis[orow[r]] : 0.f;
  }
#pragma unroll
  for (int ct = 0; ct < 8; ++ct) {
    int col = ct * 16 + lr;
#pragma unroll
    for (int r = 0; r < 4; ++r) {
      if (orow[r] < n)
        hs[(size_t)orow[r] * 128 + col] = __float2half(acc[ct][r] * dsv[r]);
    }
  }
}

// ---------------- fused aggregation: 4 rows/instruction gather ----------------
// wave = 1 node; 64 lanes = 4 row-groups (rg) x 16 col-lanes (cl, 8 cols each).
// Each gather instruction: 16 B/lane = 4 edges' rows (1 KB). Index load per-lane.
// out[i] = bf16( dis[i] * (hs[i] + sum_e hs[src_e]) + b )

__global__ __launch_bounds__(NTHREADS) void agg_kernel(
    const __half* __restrict__ hs, const int* __restrict__ rowptr,
    const int* __restrict__ csr_src, const float* __restrict__ dis,
    const float* __restrict__ b, unsigned* __restrict__ out, int n) {
  int node = blockIdx.x * (NTHREADS / 64) + (threadIdx.x >> 6);
  int lane = threadIdx.x & 63;
  if (node >= n) return;
  const int rg = lane >> 4;   // 0..3
  const int cl = lane & 15;   // cols 8*cl .. 8*cl+7
  const int r0 = rowptr[node], r1 = rowptr[node + 1];
  const float di = dis[node];

  float2 a0 = {0.f, 0.f}, a1 = {0.f, 0.f}, a2 = {0.f, 0.f}, a3 = {0.f, 0.f};
  float2 c0 = {0.f, 0.f}, c1 = {0.f, 0.f}, c2 = {0.f, 0.f}, c3 = {0.f, 0.f};

  // self loop: row-group 0 loads node's own row
  if (rg == 0) {
    uint4 v = *(const uint4*)(hs + (size_t)node * 128 + cl * 8);
    float2 f;
    f = h2u(v.x); a0.x += f.x; a0.y += f.y;
    f = h2u(v.y); a1.x += f.x; a1.y += f.y;
    f = h2u(v.z); a2.x += f.x; a2.y += f.y;
    f = h2u(v.w); a3.x += f.x; a3.y += f.y;
  }

  int e = r0;
  // 8 edges per iter: 2 gather instructions
  for (; e + 7 < r1; e += 8) {
    int s0 = csr_src[e + rg];
    int s1 = csr_src[e + 4 + rg];
    uint4 v0 = *(const uint4*)(hs + (size_t)s0 * 128 + cl * 8);
    uint4 v1 = *(const uint4*)(hs + (size_t)s1 * 128 + cl * 8);
    float2 f;
    f = h2u(v0.x); a0.x += f.x; a0.y += f.y;
    f = h2u(v0.y); a1.x += f.x; a1.y += f.y;
    f = h2u(v0.z); a2.x += f.x; a2.y += f.y;
    f = h2u(v0.w); a3.x += f.x; a3.y += f.y;
    f = h2u(v1.x); c0.x += f.x; c0.y += f.y;
    f = h2u(v1.y); c1.x += f.x; c1.y += f.y;
    f = h2u(v1.z); c2.x += f.x; c2.y += f.y;
    f = h2u(v1.w); c3.x += f.x; c3.y += f.y;
  }
  // 4-edge step
  for (; e + 3 < r1; e += 4) {
    int s0 = csr_src[e + rg];
    uint4 v0 = *(const uint4*)(hs + (size_t)s0 * 128 + cl * 8);
    float2 f;
    f = h2u(v0.x); a0.x += f.x; a0.y += f.y;
    f = h2u(v0.y); a1.x += f.x; a1.y += f.y;
    f = h2u(v0.z); a2.x += f.x; a2.y += f.y;
    f = h2u(v0.w); a3.x += f.x; a3.y += f.y;
  }
  // tail: predicated per row-group
  if (e < r1) {
    int idx = e + rg;
    if (idx < r1) {
      int s0 = csr_src[idx];
      uint4 v0 = *(const uint4*)(hs + (size_t)s0 * 128 + cl * 8);
      float2 f;
      f = h2u(v0.x); a0.x += f.x; a0.y += f.y;
      f = h2u(v0.y); a1.x += f.x; a1.y += f.y;
      f = h2u(v0.z); a2.x += f.x; a2.y += f.y;
      f = h2u(v0.w); a3.x += f.x; a3.y += f.y;
    }
  }

  a0.x += c0.x; a0.y += c0.y;
  a1.x += c1.x; a1.y += c1.y;
  a2.x += c2.x; a2.y += c2.y;
  a3.x += c3.x; a3.y += c3.y;

  // cross row-group reduce (rg stride = 16 lanes)
  a0.x += __shfl_down(a0.x, 32); a0.y += __shfl_down(a0.y, 32);
  a1.x += __shfl_down(a1.x, 32); a1.y += __shfl_down(a1.y, 32);
  a2.x += __shfl_down(a2.x, 32); a2.y += __shfl_down(a2.y, 32);
  a3.x += __shfl_down(a3.x, 32); a3.y += __shfl_down(a3.y, 32);
  a0.x += __shfl_down(a0.x, 16); a0.y += __shfl_down(a0.y, 16);
  a1.x += __shfl_down(a1.x, 16); a1.y += __shfl_down(a1.y, 16);
  a2.x += __shfl_down(a2.x, 16); a2.y += __shfl_down(a2.y, 16);
  a3.x += __shfl_down(a3.x, 16); a3.y += __shfl_down(a3.y, 16);

  if (lane < 16) {
    const float* bp = &b[cl * 8];
    float4 bb0 = *(const float4*)bp;
    float4 bb1 = *(const float4*)(bp + 4);
    uint4 w;
    w.x = (unsigned)f32_bf16(fmaf(a0.x, di, bb0.x)) |
          ((unsigned)f32_bf16(fmaf(a0.y, di, bb0.y)) << 16);
    w.y = (unsigned)f32_bf16(fmaf(a1.x, di, bb0.z)) |
          ((unsigned)f32_bf16(fmaf(a1.y, di, bb0.w)) << 16);
    w.z = (unsigned)f32_bf16(fmaf(a2.x, di, bb1.x)) |
          ((unsigned)f32_bf16(fmaf(a2.y, di, bb1.y)) << 16);
    w.w = (unsigned)f32_bf16(fmaf(a3.x, di, bb1.z)) |
          ((unsigned)f32_bf16(fmaf(a3.y, di, bb1.w)) << 16);
    *(uint4*)(out + (size_t)node * 64 + cl * 4) = w;
  }
}

// ---------------- pooling: chunked segment-sum (batch sorted, bf16 input) ----------------

__global__ __launch_bounds__(NTHREADS) void pool_kernel(
    const unsigned* __restrict__ h, const int* __restrict__ batch,
    float* __restrict__ sums, int n) {
  int wid = blockIdx.x * (NTHREADS / 64) + (threadIdx.x >> 6);
  int lane = threadIdx.x & 63;
  int i0 = wid * POOL_CHUNK;
  if (i0 >= n) return;
  int i1 = min(i0 + POOL_CHUNK, n);

  int g = batch[i0];
  float2 acc = make_float2(0.f, 0.f);
  for (int i = i0; i < i1; ++i) {
    int gi = batch[i];
    if (gi != g) {
      float* sp = &sums[g * 128 + lane * 2];
      atomicAdd(sp, acc.x);
      atomicAdd(sp + 1, acc.y);
      acc = make_float2(0.f, 0.f);
      g = gi;
    }
    unsigned v = h[(size_t)i * 64 + lane];
    acc.x += __uint_as_float(v << 16);
    acc.y += __uint_as_float(v & 0xFFFF0000u);
  }
  float* sp = &sums[g * 128 + lane * 2];
  atomicAdd(sp, acc.x);
  atomicAdd(sp + 1, acc.y);
}

// ---------------- final FC (graph count via in-kernel binary search) ----------------

__global__ __launch_bounds__(64) void fc_kernel(
    const float* __restrict__ sums, const int* __restrict__ batch,
    const float* __restrict__ fcW, const float* __restrict__ fcb,
    float* __restrict__ out, int n) {
  int g = blockIdx.x;
  int lane = threadIdx.x;
  float2 v = *(const float2*)&sums[g * 128 + lane * 2];
  float2 w = *(const float2*)&fcW[lane * 2];
  float p = v.x * w.x + v.y * w.y;
#pragma unroll
  for (int off = 32; off > 0; off >>= 1) p += __shfl_down(p, off);

  int lb = 0;
  if (lane < 2) {
    int key = g + lane;
    int lo = 0, hi = n;
    while (lo < hi) {
      int mid = (lo + hi) >> 1;
      if (batch[mid] < key) lo = mid + 1; else hi = mid;
    }
    lb = lo;
  }
  int lb0 = __shfl(lb, 0);
  int lb1 = __shfl(lb, 1);
  if (lane == 0) {
    float c = (float)(lb1 - lb0);
    out[g] = p / fmaxf(c, 1.0f) + fcb[0];
  }
}

extern "C" void kernel_launch(void* const* d_in, const int* in_sizes, int n_in,
                              void* d_out, int out_size, void* d_ws, size_t ws_size,
                              hipStream_t stream) {
  const float* x   = (const float*)d_in[0];
  const int* eidx  = (const int*)d_in[1];
  const int* batch = (const int*)d_in[2];
  const float* W0  = (const float*)d_in[3];
  const float* b0  = (const float*)d_in[4];
  const float* W1  = (const float*)d_in[5];
  const float* b1  = (const float*)d_in[6];
  const float* W2  = (const float*)d_in[7];
  const float* b2  = (const float*)d_in[8];
  const float* fcW = (const float*)d_in[9];
  const float* fcb = (const float*)d_in[10];
  float* out = (float*)d_out;

  const int N = in_sizes[0] / 128;
  const int E = in_sizes[1] / 2;
  const int G = out_size;
  const int NB = (N + 255) >> 8;

  const int* src = eidx;
  const int* dst = eidx + E;

  char* ws = (char*)d_ws;
  size_t off = 0;
  auto alloc = [&](size_t bytes) {
    void* p = ws + off;
    off = (off + bytes + 255) & ~(size_t)255;
    return p;
  };
  float*          dis    = (float*)         alloc((size_t)N * 4);
  int*            rowptr = (int*)           alloc((size_t)(N + 1) * 4);
  int*            cursor = (int*)           alloc((size_t)NB * 4);
  int*            csrsrc = (int*)           alloc((size_t)E * 4);
  unsigned*       store  = (unsigned*)      alloc((size_t)NB * CAP * 4);
  __half*         hsbuf  = (__half*)        alloc((size_t)N * 128 * 2);
  unsigned*       bufA   = (unsigned*)      alloc((size_t)N * 64 * 4);
  unsigned short* wt_hi  = (unsigned short*)alloc((size_t)3 * 16384 * 2);
  unsigned short* wt_lo  = (unsigned short*)alloc((size_t)3 * 16384 * 2);
  float*          sums   = (float*)         alloc((size_t)G * 128 * 4);

  prep_w_kernel<<<192, NTHREADS, 0, stream>>>(W0, W1, W2, wt_hi, wt_lo,
                                              cursor, sums, NB, G * 128);
  bucketize_kernel<<<(E + BKT_EDGES - 1) / BKT_EDGES, NTHREADS, 0, stream>>>(
      src, dst, cursor, store, E);
  build_kernel<<<NB, NTHREADS, 0, stream>>>(
      store, cursor, rowptr, csrsrc, dis, N, E, NB);

  const int gemm_blocks = (N + 127) / 128;
  const int node_blocks = (N + 3) / 4;
  const int pool_waves = (N + POOL_CHUNK - 1) / POOL_CHUNK;

  // layer 0 (f32 input, no relu)
  gemm_mfma_kernel<false><<<gemm_blocks, GTHREADS, 0, stream>>>(
      x, wt_hi, wt_lo, dis, hsbuf, N);
  agg_kernel<<<node_blocks, NTHREADS, 0, stream>>>(
      hsbuf, rowptr, csrsrc, dis, b0, bufA, N);
  // layer 1 (bf16 input, relu)
  gemm_mfma_kernel<true><<<gemm_blocks, GTHREADS, 0, stream>>>(
      bufA, wt_hi + 16384, wt_lo + 16384, dis, hsbuf, N);
  agg_kernel<<<node_blocks, NTHREADS, 0, stream>>>(
      hsbuf, rowptr, csrsrc, dis, b1, bufA, N);
  // layer 2 (bf16 input, relu)
  gemm_mfma_kernel<true><<<gemm_blocks, GTHREADS, 0, stream>>>(
      bufA, wt_hi + 32768, wt_lo + 32768, dis, hsbuf, N);
  agg_kernel<<<node_blocks, NTHREADS, 0, stream>>>(
      hsbuf, rowptr, csrsrc, dis, b2, bufA, N);

  // pool + fc
  pool_kernel<<<(pool_waves + 3) / 4, NTHREADS, 0, stream>>>(bufA, batch, sums, N);
  fc_kernel<<<G, 64, 0, stream>>>(sums, batch, fcW, fcb, out, N);
}